// Round 4
// baseline (86.127 us; speedup 1.0000x reference)
//
#include <hip/hip_runtime.h>
#include <math.h>

// EEGSDE: OU Euler-Maruyama step with antithetic variates + ERP jump injection.
// paths[n,b,c,t] = x[b,c,t]*(1 - theta*dt) + s*sqrt(dt)*sigma*eps[n%32,b,c,t]
//                  + mask[n,b,c]*0.2*mag[n,b,c]*exp(-0.5*((t - jt[n,b,c])/10)^2)
//
// R4: FLAT memcpy-shaped mapping. One linear read stream (eps), two linear
// write streams (out, out+131MB), grid-stride over 2048 blocks so resident
// waves sweep one contiguous window (fillBuffer's 7 TB/s pattern). Rows are
// exactly 250 float4 units so a float4 never straddles a row. x + jump params
// are L2/L3-resident side loads. Exp block exec-skipped when all amps zero.

#define DT_F 0.01f
#define THETA0 2.0f
#define SIGMA0 0.5f
#define JUMP_RATE 0.1f
#define JUMP_SCALE 0.2f
#define ERP_INV_W 0.1f   // 1/10

constexpr int B_ = 16;
constexpr int C_ = 64;
constexpr int T_ = 1000;
constexpr int NH_ = 32;                         // N_paths / 2
constexpr int BC_ = B_ * C_;                    // 1024
constexpr uint32_t ROW4 = T_ / 4;               // 250 float4 per row
constexpr uint32_t TOTAL4 = (uint32_t)NH_ * BC_ * ROW4;      // 8,192,000 units
constexpr uint32_t HALF_ROWS = (uint32_t)NH_ * BC_;          // 32768 rows
constexpr size_t   HALF_OFF_F = (size_t)HALF_ROWS * T_;      // 32,768,000 floats

typedef float f32x4 __attribute__((ext_vector_type(4)));

__global__ __launch_bounds__(256, 8) void eegsde_paths_flat(
    const float* __restrict__ x,            // [B,C,T]
    const float* __restrict__ theta_scale,  // [1]
    const float* __restrict__ sigma_scale,  // [1]
    const float* __restrict__ eps,          // [NH,B,C,T] — flat linear read
    const float* __restrict__ jump_rand,    // [N,B,C]
    const float* __restrict__ jump_mag,     // [N,B,C]
    const int*   __restrict__ jump_times,   // [N,B,C]
    float* __restrict__ out)                // [N,B,C,T]
{
    const float theta = THETA0 * fabsf(theta_scale[0]);
    const float sigma = SIGMA0 * fabsf(sigma_scale[0]);
    const float a  = 1.0f - theta * DT_F;
    const float sd = sqrtf(DT_F) * sigma;

    const uint32_t stride = gridDim.x * blockDim.x;
    uint32_t g = blockIdx.x * blockDim.x + threadIdx.x;

    for (; g < TOTAL4; g += stride) {
        const uint32_t r  = g / ROW4;            // row = nh*1024 + bc
        const uint32_t tq = g - r * ROW4;        // float4 chunk within row
        const uint32_t t0 = tq * 4u;
        const uint32_t bc = r & (BC_ - 1);
        const uint32_t r1 = r + HALF_ROWS;       // antithetic partner's param row

        // Linear streaming read (the big one).
        const f32x4 e4 = *reinterpret_cast<const f32x4*>(&eps[(size_t)g * 4]);
        // L2/L3-resident side loads.
        const f32x4 x4 = *reinterpret_cast<const f32x4*>(&x[(size_t)bc * T_ + t0]);

        const float amp0 = (jump_rand[r]  < JUMP_RATE) ? (JUMP_SCALE * jump_mag[r])  : 0.0f;
        const float amp1 = (jump_rand[r1] < JUMP_RATE) ? (JUMP_SCALE * jump_mag[r1]) : 0.0f;

        const float dw0 = sd * e4.x;
        const float dw1 = sd * e4.y;
        const float dw2 = sd * e4.z;
        const float dw3 = sd * e4.w;
        const float bx0 = a * x4.x;
        const float bx1 = a * x4.y;
        const float bx2 = a * x4.z;
        const float bx3 = a * x4.w;

        float j00 = 0.f, j01 = 0.f, j02 = 0.f, j03 = 0.f;
        float j10 = 0.f, j11 = 0.f, j12 = 0.f, j13 = 0.f;
        if ((amp0 != 0.0f) || (amp1 != 0.0f)) {   // ~66% of waves skip (execz)
            const float tf0 = (float)t0;
            const float jt0 = (float)jump_times[r];
            const float jt1 = (float)jump_times[r1];
            const float d00 = (tf0        - jt0) * ERP_INV_W;
            const float d01 = (tf0 + 1.f - jt0) * ERP_INV_W;
            const float d02 = (tf0 + 2.f - jt0) * ERP_INV_W;
            const float d03 = (tf0 + 3.f - jt0) * ERP_INV_W;
            const float d10 = (tf0        - jt1) * ERP_INV_W;
            const float d11 = (tf0 + 1.f - jt1) * ERP_INV_W;
            const float d12 = (tf0 + 2.f - jt1) * ERP_INV_W;
            const float d13 = (tf0 + 3.f - jt1) * ERP_INV_W;
            j00 = amp0 * __expf(-0.5f * d00 * d00);
            j01 = amp0 * __expf(-0.5f * d01 * d01);
            j02 = amp0 * __expf(-0.5f * d02 * d02);
            j03 = amp0 * __expf(-0.5f * d03 * d03);
            j10 = amp1 * __expf(-0.5f * d10 * d10);
            j11 = amp1 * __expf(-0.5f * d11 * d11);
            j12 = amp1 * __expf(-0.5f * d12 * d12);
            j13 = amp1 * __expf(-0.5f * d13 * d13);
        }

        f32x4 o0, o1;
        o0.x = bx0 + dw0 + j00;
        o0.y = bx1 + dw1 + j01;
        o0.z = bx2 + dw2 + j02;
        o0.w = bx3 + dw3 + j03;
        o1.x = bx0 - dw0 + j10;
        o1.y = bx1 - dw1 + j11;
        o1.z = bx2 - dw2 + j12;
        o1.w = bx3 - dw3 + j13;

        // Two linear write streams at constant 131 MB offset.
        *reinterpret_cast<f32x4*>(&out[(size_t)g * 4])               = o0;
        *reinterpret_cast<f32x4*>(&out[(size_t)g * 4 + HALF_OFF_F])  = o1;
    }
}

extern "C" void kernel_launch(void* const* d_in, const int* in_sizes, int n_in,
                              void* d_out, int out_size, void* d_ws, size_t ws_size,
                              hipStream_t stream) {
    const float* x           = (const float*)d_in[0];
    const float* theta_scale = (const float*)d_in[1];
    const float* sigma_scale = (const float*)d_in[2];
    const float* eps         = (const float*)d_in[3];
    const float* jump_rand   = (const float*)d_in[4];
    const float* jump_mag    = (const float*)d_in[5];
    const int*   jump_times  = (const int*)d_in[6];
    float* out = (float*)d_out;

    dim3 grid(2048, 1, 1);   // 8 blocks/CU, grid-stride sweep
    dim3 block(256, 1, 1);
    eegsde_paths_flat<<<grid, block, 0, stream>>>(
        x, theta_scale, sigma_scale, eps, jump_rand, jump_mag, jump_times, out);
}